// Round 1
// baseline (379.157 us; speedup 1.0000x reference)
//
#include <hip/hip_runtime.h>
#include <math.h>

// ShiftedWindowAttention 3D (Swin): 32^3 grid, C=128, heads=4, hd=32,
// window 8^3 (N=512 tokens), shift 4^3, 64 windows. fp32 baseline.
//
// ws layout (floats):
//   q   : [64][4][512][32]  @ 0         (4,194,304)
//   k   : same              @ 4194304
//   v   : same              @ 8388608
//   ao  : [64][512][128]    @ 12582912  (4,194,304)
//   bias: [4][512][512]     @ 16777216  (1,048,576)
// total 17,825,792 floats = 68 MiB

#define NTOT 262144        // 512*512

// ---------------- bias precompute: bias[h][n][m] = rpb[rpi[n*512+m]][h] ----
__global__ void k_bias(const float* __restrict__ rpb, const int* __restrict__ rpi,
                       float* __restrict__ bias_full) {
  int idx = blockIdx.x * 256 + threadIdx.x;        // (n,m) flat, 0..262143
  int t = rpi[idx];
  float4 b4 = *reinterpret_cast<const float4*>(rpb + 4 * t);
  bias_full[0 * NTOT + idx] = b4.x;
  bias_full[1 * NTOT + idx] = b4.y;
  bias_full[2 * NTOT + idx] = b4.z;
  bias_full[3 * NTOT + idx] = b4.w;
}

// ---------------- fused roll + window partition + QKV GEMM ----------------
// grid 512 = 64 windows * 8 row-tiles; block 256.
// A tile: 64 tokens x 128 ch (LDS). B: qkv_weight rows, 6 chunks of 64.
// thread (ty=tid>>4, tx=tid&15): rows = ty + rr*16, cols = tx + cc*16.
#define PADK 132
__global__ __launch_bounds__(256, 2) void k_qkv(
    const float* __restrict__ x, const float* __restrict__ w,
    const float* __restrict__ bias,
    float* __restrict__ qb, float* __restrict__ kb, float* __restrict__ vb) {
  __shared__ float As[64][PADK];
  __shared__ float Bs[64][PADK];
  const int tid = threadIdx.x;
  const int bm = blockIdx.x;
  const int win = bm >> 3, tile = bm & 7;
  const int wh = win >> 4, ww = (win >> 2) & 3, wd = win & 3;

  // stage A: 64 tokens x 128 ch, gathering through roll + window partition
#pragma unroll
  for (int i = 0; i < 8; ++i) {
    int f = i * 256 + tid;            // float4 id, 0..2047
    int row = f >> 5, k4 = f & 31;
    int n = tile * 64 + row;
    int lh = n >> 6, lw = (n >> 3) & 7, ld = n & 7;
    int sh = (wh * 8 + lh + 4) & 31;
    int sw = (ww * 8 + lw + 4) & 31;
    int sd = (wd * 8 + ld + 4) & 31;
    float4 v4 = *reinterpret_cast<const float4*>(
        x + ((sh * 32 + sw) * 32 + sd) * 128 + k4 * 4);
    *reinterpret_cast<float4*>(&As[row][k4 * 4]) = v4;
  }

  const int ty = tid >> 4, tx = tid & 15;
  const float scale = 0.17677669529663687f;   // 32^-0.5

  for (int nc = 0; nc < 6; ++nc) {
    __syncthreads();                  // protect Bs from previous chunk's readers
    const int col0 = nc * 64;
#pragma unroll
    for (int i = 0; i < 8; ++i) {
      int f = i * 256 + tid;
      int row = f >> 5, k4 = f & 31;
      *reinterpret_cast<float4*>(&Bs[row][k4 * 4]) =
          *reinterpret_cast<const float4*>(w + (col0 + row) * 128 + k4 * 4);
    }
    __syncthreads();

    float acc[4][4];
#pragma unroll
    for (int r = 0; r < 4; ++r)
#pragma unroll
      for (int c = 0; c < 4; ++c) acc[r][c] = 0.f;

#pragma unroll 4
    for (int k = 0; k < 128; k += 4) {
      float4 a[4], b4r[4];
#pragma unroll
      for (int r = 0; r < 4; ++r)
        a[r] = *reinterpret_cast<const float4*>(&As[ty + r * 16][k]);
#pragma unroll
      for (int c = 0; c < 4; ++c)
        b4r[c] = *reinterpret_cast<const float4*>(&Bs[tx + c * 16][k]);
#pragma unroll
      for (int r = 0; r < 4; ++r)
#pragma unroll
        for (int c = 0; c < 4; ++c) {
          acc[r][c] += a[r].x * b4r[c].x;
          acc[r][c] += a[r].y * b4r[c].y;
          acc[r][c] += a[r].z * b4r[c].z;
          acc[r][c] += a[r].w * b4r[c].w;
        }
    }

    // epilogue: add bias, scale q, scatter to q/k/v [win][head][n][32]
#pragma unroll
    for (int r = 0; r < 4; ++r) {
      int n = tile * 64 + ty + r * 16;
#pragma unroll
      for (int c = 0; c < 4; ++c) {
        int j = col0 + c * 16 + tx;         // 0..383
        float val = acc[r][c] + bias[j];
        int which = j >> 7;                 // 0=q 1=k 2=v
        int head = (j >> 5) & 3;
        int dd = j & 31;
        float* dst = (which == 0) ? qb : (which == 1 ? kb : vb);
        if (which == 0) val *= scale;
        dst[(((win * 4) + head) * 512 + n) * 32 + dd] = val;
      }
    }
  }
}

// ---------------- attention: flash-style, 1 query row / thread ------------
// grid 512 = 64 win * 4 heads * 2 halves; block 256 (rows half*256+tid).
__global__ __launch_bounds__(256, 2) void k_attn(
    const float* __restrict__ qb, const float* __restrict__ kb,
    const float* __restrict__ vb, const float* __restrict__ bias_full,
    float* __restrict__ ao) {
  __shared__ float Ks[128 * 32];
  __shared__ float Vs[128 * 32];
  __shared__ unsigned char regS[128];
  const int tid = threadIdx.x;
  const int b = blockIdx.x;
  const int win = b >> 3, head = (b >> 1) & 3, half = b & 1;
  const int wh = win >> 4, ww = (win >> 2) & 3, wd = win & 3;
  const int n = half * 256 + tid;

  // my row's shift-mask region id (analytic, no mask tensor)
  const int lh = n >> 6, lw = (n >> 3) & 7, ld = n & 7;
  const int rn = ((wh == 3) ? (lh < 4 ? 1 : 2) : 0) * 9 +
                 ((ww == 3) ? (lw < 4 ? 1 : 2) : 0) * 3 +
                 ((wd == 3) ? (ld < 4 ? 1 : 2) : 0);

  const float* qrow = qb + (((win * 4) + head) * 512 + n) * 32;
  float4 q4[8];
#pragma unroll
  for (int i = 0; i < 8; ++i)
    q4[i] = *reinterpret_cast<const float4*>(qrow + i * 4);

  float m_run = -1e30f, l_run = 0.f;
  float4 o4[8];
#pragma unroll
  for (int i = 0; i < 8; ++i) o4[i] = make_float4(0.f, 0.f, 0.f, 0.f);

  const float* kbase = kb + (size_t)(((win * 4) + head) * 512) * 32;
  const float* vbase = vb + (size_t)(((win * 4) + head) * 512) * 32;
  const float* brow = bias_full + (size_t)(head * 512 + n) * 512;

  for (int kt = 0; kt < 4; ++kt) {
    __syncthreads();
#pragma unroll
    for (int i = 0; i < 4; ++i) {
      int f = i * 256 + tid;            // 1024 float4 per K and V tile
      *reinterpret_cast<float4*>(&Ks[f * 4]) =
          *reinterpret_cast<const float4*>(kbase + kt * 128 * 32 + f * 4);
      *reinterpret_cast<float4*>(&Vs[f * 4]) =
          *reinterpret_cast<const float4*>(vbase + kt * 128 * 32 + f * 4);
    }
    if (tid < 128) {
      int m = kt * 128 + tid;
      int mh = m >> 6, mw = (m >> 3) & 7, md = m & 7;
      regS[tid] = (unsigned char)(((wh == 3) ? (mh < 4 ? 1 : 2) : 0) * 9 +
                                  ((ww == 3) ? (mw < 4 ? 1 : 2) : 0) * 3 +
                                  ((wd == 3) ? (md < 4 ? 1 : 2) : 0));
    }
    __syncthreads();

    for (int jc = 0; jc < 8; ++jc) {    // 8 chunks of 16 keys
      float barr[16];
#pragma unroll
      for (int i = 0; i < 4; ++i)
        *reinterpret_cast<float4*>(&barr[i * 4]) =
            *reinterpret_cast<const float4*>(brow + kt * 128 + jc * 16 + i * 4);

      float s[16];
#pragma unroll
      for (int jj = 0; jj < 16; ++jj) {
        const float* kr = &Ks[(jc * 16 + jj) * 32];
        float dot = 0.f;
#pragma unroll
        for (int i = 0; i < 8; ++i) {
          float4 kk = *reinterpret_cast<const float4*>(kr + i * 4);
          dot += q4[i].x * kk.x + q4[i].y * kk.y + q4[i].z * kk.z + q4[i].w * kk.w;
        }
        int rm = regS[jc * 16 + jj];
        s[jj] = dot + barr[jj] + ((rm == rn) ? 0.f : -100.f);
      }

      float cm = s[0];
#pragma unroll
      for (int jj = 1; jj < 16; ++jj) cm = fmaxf(cm, s[jj]);
      float m_new = fmaxf(m_run, cm);
      float alpha = __expf(m_run - m_new);
      l_run *= alpha;
#pragma unroll
      for (int i = 0; i < 8; ++i) {
        o4[i].x *= alpha; o4[i].y *= alpha; o4[i].z *= alpha; o4[i].w *= alpha;
      }
#pragma unroll
      for (int jj = 0; jj < 16; ++jj) {
        float p = __expf(s[jj] - m_new);
        l_run += p;
        const float* vr = &Vs[(jc * 16 + jj) * 32];
#pragma unroll
        for (int i = 0; i < 8; ++i) {
          float4 vv = *reinterpret_cast<const float4*>(vr + i * 4);
          o4[i].x += p * vv.x; o4[i].y += p * vv.y;
          o4[i].z += p * vv.z; o4[i].w += p * vv.w;
        }
      }
      m_run = m_new;
    }
  }

  const float inv = 1.f / l_run;
  float* orow = ao + (size_t)(win * 512 + n) * 128 + head * 32;
#pragma unroll
  for (int i = 0; i < 8; ++i) {
    float4 t = o4[i];
    t.x *= inv; t.y *= inv; t.z *= inv; t.w *= inv;
    *reinterpret_cast<float4*>(orow + i * 4) = t;
  }
}

// ---------------- proj GEMM + reverse partition + reverse roll ------------
// grid 512 = 64 windows * 8 row-tiles; block 256. dst coords == src coords.
__global__ __launch_bounds__(256, 2) void k_proj(
    const float* __restrict__ ao, const float* __restrict__ w,
    const float* __restrict__ bias, float* __restrict__ out) {
  __shared__ float As[64][PADK];
  __shared__ float Bs[64][PADK];
  const int tid = threadIdx.x;
  const int bm = blockIdx.x;
  const int win = bm >> 3, tile = bm & 7;
  const int wh = win >> 4, ww = (win >> 2) & 3, wd = win & 3;

#pragma unroll
  for (int i = 0; i < 8; ++i) {
    int f = i * 256 + tid;
    int row = f >> 5, k4 = f & 31;
    *reinterpret_cast<float4*>(&As[row][k4 * 4]) =
        *reinterpret_cast<const float4*>(
            ao + (size_t)(win * 512 + tile * 64 + row) * 128 + k4 * 4);
  }

  const int ty = tid >> 4, tx = tid & 15;
  for (int nc = 0; nc < 2; ++nc) {
    __syncthreads();
    const int col0 = nc * 64;
#pragma unroll
    for (int i = 0; i < 8; ++i) {
      int f = i * 256 + tid;
      int row = f >> 5, k4 = f & 31;
      *reinterpret_cast<float4*>(&Bs[row][k4 * 4]) =
          *reinterpret_cast<const float4*>(w + (col0 + row) * 128 + k4 * 4);
    }
    __syncthreads();

    float acc[4][4];
#pragma unroll
    for (int r = 0; r < 4; ++r)
#pragma unroll
      for (int c = 0; c < 4; ++c) acc[r][c] = 0.f;

#pragma unroll 4
    for (int k = 0; k < 128; k += 4) {
      float4 a[4], b4r[4];
#pragma unroll
      for (int r = 0; r < 4; ++r)
        a[r] = *reinterpret_cast<const float4*>(&As[ty + r * 16][k]);
#pragma unroll
      for (int c = 0; c < 4; ++c)
        b4r[c] = *reinterpret_cast<const float4*>(&Bs[tx + c * 16][k]);
#pragma unroll
      for (int r = 0; r < 4; ++r)
#pragma unroll
        for (int c = 0; c < 4; ++c) {
          acc[r][c] += a[r].x * b4r[c].x;
          acc[r][c] += a[r].y * b4r[c].y;
          acc[r][c] += a[r].z * b4r[c].z;
          acc[r][c] += a[r].w * b4r[c].w;
        }
    }

#pragma unroll
    for (int r = 0; r < 4; ++r) {
      int n = tile * 64 + ty + r * 16;
      int lh = n >> 6, lw = (n >> 3) & 7, ld = n & 7;
      int dh = (wh * 8 + lh + 4) & 31;
      int dw = (ww * 8 + lw + 4) & 31;
      int dd = (wd * 8 + ld + 4) & 31;
      float* orow = out + (size_t)((dh * 32 + dw) * 32 + dd) * 128;
#pragma unroll
      for (int c = 0; c < 4; ++c) {
        int j = col0 + c * 16 + tx;
        orow[j] = acc[r][c] + bias[j];
      }
    }
  }
}

extern "C" void kernel_launch(void* const* d_in, const int* in_sizes, int n_in,
                              void* d_out, int out_size, void* d_ws, size_t ws_size,
                              hipStream_t stream) {
  const float* x    = (const float*)d_in[0];
  const float* qkvw = (const float*)d_in[1];
  const float* qkvb = (const float*)d_in[2];
  const float* pw   = (const float*)d_in[3];
  const float* pb   = (const float*)d_in[4];
  const float* rpb  = (const float*)d_in[5];
  const int*   rpi  = (const int*)d_in[6];
  float* out = (float*)d_out;

  float* wsf = (float*)d_ws;
  float* q  = wsf;
  float* k  = wsf + 4194304;
  float* v  = wsf + 8388608;
  float* ao = wsf + 12582912;
  float* bf = wsf + 16777216;

  hipLaunchKernelGGL(k_bias, dim3(1024), dim3(256), 0, stream, rpb, rpi, bf);
  hipLaunchKernelGGL(k_qkv,  dim3(512),  dim3(256), 0, stream, x, qkvw, qkvb, q, k, v);
  hipLaunchKernelGGL(k_attn, dim3(512),  dim3(256), 0, stream, q, k, v, bf, ao);
  hipLaunchKernelGGL(k_proj, dim3(512),  dim3(256), 0, stream, ao, pw, pb, out);
}

// Round 2
// 213.753 us; speedup vs baseline: 1.7738x; 1.7738x over previous
//
#include <hip/hip_runtime.h>
#include <hip/hip_bf16.h>
#include <math.h>

// ShiftedWindowAttention 3D (Swin): 32^3, C=128, heads=4, hd=32, window 8^3
// (N=512), shift 4^3, 64 windows. Round 2: attention on bf16 MFMA
// (v_mfma_f32_32x32x16_bf16, swapped-operand S^T / O^T scheme).
//
// ws layout (bytes):
//   qb  bf16 [64*4][512][32]  @ 0          (8,388,608)
//   kb  bf16 [64*4][512][32]  @ 8388608
//   vb  bf16 [64*4][32][512]  @ 16777216   (V stored TRANSPOSED per win-head)
//   ao  f32  [64][512][128]   @ 25165824   (16,777,216)
//   bias f32 [4][512][512]    @ 41943040   (4,194,304)

#define NTOT 262144

typedef float    f32x16 __attribute__((ext_vector_type(16)));
typedef __bf16   bf16x8 __attribute__((ext_vector_type(8)));
typedef unsigned int u32x4 __attribute__((ext_vector_type(4)));

__device__ __forceinline__ unsigned int pkbf16(float a, float b) {
  __hip_bfloat16 x = __float2bfloat16(a), y = __float2bfloat16(b);
  return (unsigned int)__builtin_bit_cast(unsigned short, x) |
         ((unsigned int)__builtin_bit_cast(unsigned short, y) << 16);
}

// ---------------- bias precompute: bias[h][n][m] = rpb[rpi[n*512+m]][h] ----
__global__ void k_bias(const float* __restrict__ rpb, const int* __restrict__ rpi,
                       float* __restrict__ bias_full) {
  int idx = blockIdx.x * 256 + threadIdx.x;
  int t = rpi[idx];
  float4 b4 = *reinterpret_cast<const float4*>(rpb + 4 * t);
  bias_full[0 * NTOT + idx] = b4.x;
  bias_full[1 * NTOT + idx] = b4.y;
  bias_full[2 * NTOT + idx] = b4.z;
  bias_full[3 * NTOT + idx] = b4.w;
}

// ---------------- fused roll + window partition + QKV GEMM (fp32 core) ----
// epilogue now emits bf16: q (pre-scaled) / k as [wh][512][32], v as [wh][32][512].
#define PADK 132
__global__ __launch_bounds__(256, 2) void k_qkv(
    const float* __restrict__ x, const float* __restrict__ w,
    const float* __restrict__ bias,
    __hip_bfloat16* __restrict__ qb, __hip_bfloat16* __restrict__ kb,
    __hip_bfloat16* __restrict__ vb) {
  __shared__ float As[64][PADK];
  __shared__ float Bs[64][PADK];
  const int tid = threadIdx.x;
  const int bm = blockIdx.x;
  const int win = bm >> 3, tile = bm & 7;
  const int wh = win >> 4, ww = (win >> 2) & 3, wd = win & 3;

#pragma unroll
  for (int i = 0; i < 8; ++i) {
    int f = i * 256 + tid;
    int row = f >> 5, k4 = f & 31;
    int n = tile * 64 + row;
    int lh = n >> 6, lw = (n >> 3) & 7, ld = n & 7;
    int sh = (wh * 8 + lh + 4) & 31;
    int sw = (ww * 8 + lw + 4) & 31;
    int sd = (wd * 8 + ld + 4) & 31;
    *reinterpret_cast<float4*>(&As[row][k4 * 4]) =
        *reinterpret_cast<const float4*>(x + ((sh * 32 + sw) * 32 + sd) * 128 + k4 * 4);
  }

  const int ty = tid >> 4, tx = tid & 15;
  const float scale = 0.17677669529663687f;

  for (int nc = 0; nc < 6; ++nc) {
    __syncthreads();
    const int col0 = nc * 64;
#pragma unroll
    for (int i = 0; i < 8; ++i) {
      int f = i * 256 + tid;
      int row = f >> 5, k4 = f & 31;
      *reinterpret_cast<float4*>(&Bs[row][k4 * 4]) =
          *reinterpret_cast<const float4*>(w + (col0 + row) * 128 + k4 * 4);
    }
    __syncthreads();

    float acc[4][4];
#pragma unroll
    for (int r = 0; r < 4; ++r)
#pragma unroll
      for (int c = 0; c < 4; ++c) acc[r][c] = 0.f;

#pragma unroll 4
    for (int k = 0; k < 128; k += 4) {
      float4 a[4], b4r[4];
#pragma unroll
      for (int r = 0; r < 4; ++r)
        a[r] = *reinterpret_cast<const float4*>(&As[ty + r * 16][k]);
#pragma unroll
      for (int c = 0; c < 4; ++c)
        b4r[c] = *reinterpret_cast<const float4*>(&Bs[tx + c * 16][k]);
#pragma unroll
      for (int r = 0; r < 4; ++r)
#pragma unroll
        for (int c = 0; c < 4; ++c) {
          acc[r][c] += a[r].x * b4r[c].x;
          acc[r][c] += a[r].y * b4r[c].y;
          acc[r][c] += a[r].z * b4r[c].z;
          acc[r][c] += a[r].w * b4r[c].w;
        }
    }

#pragma unroll
    for (int r = 0; r < 4; ++r) {
      int n = tile * 64 + ty + r * 16;
#pragma unroll
      for (int c = 0; c < 4; ++c) {
        int j = col0 + c * 16 + tx;
        float val = acc[r][c] + bias[j];
        int which = j >> 7;
        int head = (j >> 5) & 3;
        int dd = j & 31;
        int whb = win * 4 + head;
        if (which == 0) {
          qb[((size_t)whb * 512 + n) * 32 + dd] = __float2bfloat16(val * scale);
        } else if (which == 1) {
          kb[((size_t)whb * 512 + n) * 32 + dd] = __float2bfloat16(val);
        } else {
          vb[((size_t)whb * 32 + dd) * 512 + n] = __float2bfloat16(val);
        }
      }
    }
  }
}

// ---------------- attention: bf16 MFMA, swapped-operand flash -------------
// block = (win, head, q-quarter): 4 waves x 32 queries. grid 1024, block 256.
// Per 64-key chunk: K [64][32] (rows padded to 80B) and V^T [32][64] (rows
// padded to 144B) in LDS; two 32-key sub-tiles:
//   S^T = mfma(Kfrag, Qfrag)  -> lane&31 = query col, regs+lane>>5 = keys
//   online softmax (in-lane + one shfl_xor(32))
//   P^T B-frag via pack-bf16 + shfl_xor(32) half-exchange
//   O^T += mfma(Vtfrag, Pfrag)
__global__ __launch_bounds__(256) void k_attn(
    const __hip_bfloat16* __restrict__ qb, const __hip_bfloat16* __restrict__ kb,
    const __hip_bfloat16* __restrict__ vb, const float* __restrict__ bias_full,
    float* __restrict__ ao) {
  __shared__ unsigned short Ks[64 * 40];   // 64 keys x 32 ch, stride 40 u16 (80B)
  __shared__ unsigned short Vs[32 * 72];   // 32 d x 64 keys, stride 72 u16 (144B)
  __shared__ unsigned char regid[512];

  const int tid = threadIdx.x;
  const int b = blockIdx.x;
  const int win = b >> 4, head = (b >> 2) & 3, qblk = b & 3;
  const int wh = win >> 4, ww = (win >> 2) & 3, wd = win & 3;
  const int wave = tid >> 6, lane = tid & 63;
  const int lq = lane & 31, h = lane >> 5;
  const int q = qblk * 128 + wave * 32 + lq;

  // key region ids for this window (shift mask), all 512 tokens
#pragma unroll
  for (int i = 0; i < 2; ++i) {
    int n = tid + i * 256;
    int lh = n >> 6, lw = (n >> 3) & 7, ld = n & 7;
    regid[n] = (unsigned char)(((wh == 3) ? (lh < 4 ? 1 : 2) : 0) * 9 +
                               ((ww == 3) ? (lw < 4 ? 1 : 2) : 0) * 3 +
                               ((wd == 3) ? (ld < 4 ? 1 : 2) : 0));
  }
  const int qlh = q >> 6, qlw = (q >> 3) & 7, qld = q & 7;
  const unsigned int rn =
      (unsigned)(((wh == 3) ? (qlh < 4 ? 1 : 2) : 0) * 9 +
                 ((ww == 3) ? (qlw < 4 ? 1 : 2) : 0) * 3 +
                 ((wd == 3) ? (qld < 4 ? 1 : 2) : 0));

  const size_t whb = (size_t)(win * 4 + head);
  const __hip_bfloat16* qrow = qb + (whb * 512 + q) * 32;
  bf16x8 qf0 = __builtin_bit_cast(bf16x8, *(const u32x4*)(qrow + h * 8));
  bf16x8 qf1 = __builtin_bit_cast(bf16x8, *(const u32x4*)(qrow + 16 + h * 8));

  const __hip_bfloat16* kg = kb + whb * 512 * 32;
  const __hip_bfloat16* vg = vb + whb * 32 * 512;
  const float* brow = bias_full + ((size_t)head * 512 + q) * 512;

  float m_run = -3.0e38f, l_run = 0.f;
  f32x16 o;
#pragma unroll
  for (int r = 0; r < 16; ++r) o[r] = 0.f;

  for (int chk = 0; chk < 8; ++chk) {
    __syncthreads();
    {
      int row = tid >> 2, seg = tid & 3;     // K: 64 rows x 4 segs
      *(u32x4*)(&Ks[row * 40 + seg * 8]) =
          *(const u32x4*)(kg + (chk * 64 + row) * 32 + seg * 8);
      int d = tid >> 3, seg2 = tid & 7;      // Vt: 32 rows x 8 segs
      *(u32x4*)(&Vs[d * 72 + seg2 * 8]) =
          *(const u32x4*)(vg + d * 512 + chk * 64 + seg2 * 8);
    }
    __syncthreads();

#pragma unroll
    for (int sub = 0; sub < 2; ++sub) {
      const int kbase = chk * 64 + sub * 32;

      bf16x8 kf0 = __builtin_bit_cast(bf16x8,
          *(const u32x4*)(&Ks[(sub * 32 + lq) * 40 + h * 8]));
      bf16x8 kf1 = __builtin_bit_cast(bf16x8,
          *(const u32x4*)(&Ks[(sub * 32 + lq) * 40 + 16 + h * 8]));
      f32x16 c;
#pragma unroll
      for (int r = 0; r < 16; ++r) c[r] = 0.f;
      c = __builtin_amdgcn_mfma_f32_32x32x16_bf16(kf0, qf0, c, 0, 0, 0);
      c = __builtin_amdgcn_mfma_f32_32x32x16_bf16(kf1, qf1, c, 0, 0, 0);

      // bias (4 x float4) + mask regions (4 x u32 of packed bytes)
      float bias_s[16];
      unsigned int rm4[4];
#pragma unroll
      for (int j = 0; j < 4; ++j) {
        float4 b4 = *(const float4*)(brow + kbase + h * 4 + j * 8);
        bias_s[j * 4 + 0] = b4.x; bias_s[j * 4 + 1] = b4.y;
        bias_s[j * 4 + 2] = b4.z; bias_s[j * 4 + 3] = b4.w;
        rm4[j] = *(const unsigned int*)(&regid[kbase + h * 4 + j * 8]);
      }

      float s[16];
#pragma unroll
      for (int r = 0; r < 16; ++r) {
        int j = r >> 2, i = r & 3;
        float mval = (((rm4[j] >> (8 * i)) & 255u) == rn) ? 0.f : -100.f;
        s[r] = c[r] + bias_s[r] + mval;
      }

      float tmax = s[0];
#pragma unroll
      for (int r = 1; r < 16; ++r) tmax = fmaxf(tmax, s[r]);
      tmax = fmaxf(tmax, __shfl_xor(tmax, 32, 64));
      float m_new = fmaxf(m_run, tmax);
      float alpha = __expf(m_run - m_new);
      float p[16], lsum = 0.f;
#pragma unroll
      for (int r = 0; r < 16; ++r) { p[r] = __expf(s[r] - m_new); lsum += p[r]; }
      lsum += __shfl_xor(lsum, 32, 64);
      l_run = l_run * alpha + lsum;
      m_run = m_new;
#pragma unroll
      for (int r = 0; r < 16; ++r) o[r] *= alpha;

      unsigned int bw[8];
#pragma unroll
      for (int g = 0; g < 8; ++g) bw[g] = pkbf16(p[2 * g], p[2 * g + 1]);

#pragma unroll
      for (int kc = 0; kc < 2; ++kc) {
        unsigned int b0 = bw[kc * 4 + 0], b1 = bw[kc * 4 + 1];
        unsigned int b2 = bw[kc * 4 + 2], b3 = bw[kc * 4 + 3];
        unsigned int sb0 = __shfl_xor(b0, 32, 64), sb1 = __shfl_xor(b1, 32, 64);
        unsigned int sb2 = __shfl_xor(b2, 32, 64), sb3 = __shfl_xor(b3, 32, 64);
        u32x4 pw;
        pw.x = h ? sb2 : b0;
        pw.y = h ? sb3 : b1;
        pw.z = h ? b2 : sb0;
        pw.w = h ? b3 : sb1;
        bf16x8 pf = __builtin_bit_cast(bf16x8, pw);
        bf16x8 vf = __builtin_bit_cast(bf16x8,
            *(const u32x4*)(&Vs[lq * 72 + sub * 32 + kc * 16 + h * 8]));
        o = __builtin_amdgcn_mfma_f32_32x32x16_bf16(vf, pf, o, 0, 0, 0);
      }
    }
  }

  const float inv = 1.f / l_run;
  float* orow = ao + ((size_t)(win * 512 + q)) * 128 + head * 32;
#pragma unroll
  for (int j = 0; j < 4; ++j) {
    int d0 = j * 8 + h * 4;
    float4 t = make_float4(o[j * 4] * inv, o[j * 4 + 1] * inv,
                           o[j * 4 + 2] * inv, o[j * 4 + 3] * inv);
    *(float4*)(orow + d0) = t;
  }
}

// ---------------- proj GEMM + reverse partition + reverse roll ------------
__global__ __launch_bounds__(256, 2) void k_proj(
    const float* __restrict__ ao, const float* __restrict__ w,
    const float* __restrict__ bias, float* __restrict__ out) {
  __shared__ float As[64][PADK];
  __shared__ float Bs[64][PADK];
  const int tid = threadIdx.x;
  const int bm = blockIdx.x;
  const int win = bm >> 3, tile = bm & 7;
  const int wh = win >> 4, ww = (win >> 2) & 3, wd = win & 3;

#pragma unroll
  for (int i = 0; i < 8; ++i) {
    int f = i * 256 + tid;
    int row = f >> 5, k4 = f & 31;
    *reinterpret_cast<float4*>(&As[row][k4 * 4]) =
        *reinterpret_cast<const float4*>(
            ao + (size_t)(win * 512 + tile * 64 + row) * 128 + k4 * 4);
  }

  const int ty = tid >> 4, tx = tid & 15;
  for (int nc = 0; nc < 2; ++nc) {
    __syncthreads();
    const int col0 = nc * 64;
#pragma unroll
    for (int i = 0; i < 8; ++i) {
      int f = i * 256 + tid;
      int row = f >> 5, k4 = f & 31;
      *reinterpret_cast<float4*>(&Bs[row][k4 * 4]) =
          *reinterpret_cast<const float4*>(w + (col0 + row) * 128 + k4 * 4);
    }
    __syncthreads();

    float acc[4][4];
#pragma unroll
    for (int r = 0; r < 4; ++r)
#pragma unroll
      for (int c = 0; c < 4; ++c) acc[r][c] = 0.f;

#pragma unroll 4
    for (int k = 0; k < 128; k += 4) {
      float4 a[4], b4r[4];
#pragma unroll
      for (int r = 0; r < 4; ++r)
        a[r] = *reinterpret_cast<const float4*>(&As[ty + r * 16][k]);
#pragma unroll
      for (int c = 0; c < 4; ++c)
        b4r[c] = *reinterpret_cast<const float4*>(&Bs[tx + c * 16][k]);
#pragma unroll
      for (int r = 0; r < 4; ++r)
#pragma unroll
        for (int c = 0; c < 4; ++c) {
          acc[r][c] += a[r].x * b4r[c].x;
          acc[r][c] += a[r].y * b4r[c].y;
          acc[r][c] += a[r].z * b4r[c].z;
          acc[r][c] += a[r].w * b4r[c].w;
        }
    }

#pragma unroll
    for (int r = 0; r < 4; ++r) {
      int n = tile * 64 + ty + r * 16;
      int lh = n >> 6, lw = (n >> 3) & 7, ld = n & 7;
      int dh = (wh * 8 + lh + 4) & 31;
      int dw = (ww * 8 + lw + 4) & 31;
      int dd = (wd * 8 + ld + 4) & 31;
      float* orow = out + (size_t)((dh * 32 + dw) * 32 + dd) * 128;
#pragma unroll
      for (int c = 0; c < 4; ++c) {
        int j = col0 + c * 16 + tx;
        orow[j] = acc[r][c] + bias[j];
      }
    }
  }
}

extern "C" void kernel_launch(void* const* d_in, const int* in_sizes, int n_in,
                              void* d_out, int out_size, void* d_ws, size_t ws_size,
                              hipStream_t stream) {
  const float* x    = (const float*)d_in[0];
  const float* qkvw = (const float*)d_in[1];
  const float* qkvb = (const float*)d_in[2];
  const float* pw   = (const float*)d_in[3];
  const float* pb   = (const float*)d_in[4];
  const float* rpb  = (const float*)d_in[5];
  const int*   rpi  = (const int*)d_in[6];
  float* out = (float*)d_out;

  char* base = (char*)d_ws;
  __hip_bfloat16* qbuf = (__hip_bfloat16*)(base);
  __hip_bfloat16* kbuf = (__hip_bfloat16*)(base + 8388608);
  __hip_bfloat16* vbuf = (__hip_bfloat16*)(base + 16777216);
  float* ao = (float*)(base + 25165824);
  float* bf = (float*)(base + 41943040);

  hipLaunchKernelGGL(k_bias, dim3(1024), dim3(256), 0, stream, rpb, rpi, bf);
  hipLaunchKernelGGL(k_qkv,  dim3(512),  dim3(256), 0, stream, x, qkvw, qkvb, qbuf, kbuf, vbuf);
  hipLaunchKernelGGL(k_attn, dim3(1024), dim3(256), 0, stream, qbuf, kbuf, vbuf, bf, ao);
  hipLaunchKernelGGL(k_proj, dim3(512),  dim3(256), 0, stream, ao, pw, pb, out);
}

// Round 5
// 153.383 us; speedup vs baseline: 2.4720x; 1.3936x over previous
//
#include <hip/hip_runtime.h>
#include <hip/hip_bf16.h>
#include <math.h>

// ShiftedWindowAttention 3D (Swin): 32^3, C=128, heads=4, hd=32, window 8^3
// (N=512), shift 4^3, 64 windows.
// Round 3 kernel, third submission (R3/R4 benches were GPU-acquisition
// timeouts — no data, no edits):
// QKV + proj GEMMs on fp16 MFMA (v_mfma_f32_32x32x16_f16),
// K=128 single-stage tiles, XOR-swizzled LDS. Attention unchanged (bf16 MFMA)
// except ao is now written fp16 for proj's A-staging.
//
// ws layout (bytes):
//   qb  bf16 [256][512][32]  @ 0          (8,388,608)
//   kb  bf16 [256][512][32]  @ 8388608
//   vb  bf16 [256][32][512]  @ 16777216   (V transposed per win-head)
//   ao  f16  [64*512][128]   @ 25165824   (8,388,608)
//   bias f32 [4][512][512]   @ 33554432   (4,194,304)
//   wq  f16  [384][128]      @ 37748736   (98,304)
//   wp  f16  [128][128]      @ 37847040   (32,768)

#define NTOT 262144

typedef float     f32x16 __attribute__((ext_vector_type(16)));
typedef __bf16    bf16x8 __attribute__((ext_vector_type(8)));
typedef _Float16  f16x8  __attribute__((ext_vector_type(8)));
typedef _Float16  f16x4  __attribute__((ext_vector_type(4)));
typedef unsigned int u32x4 __attribute__((ext_vector_type(4)));

__device__ __forceinline__ unsigned int pkbf16(float a, float b) {
  __hip_bfloat16 x = __float2bfloat16(a), y = __float2bfloat16(b);
  return (unsigned int)__builtin_bit_cast(unsigned short, x) |
         ((unsigned int)__builtin_bit_cast(unsigned short, y) << 16);
}

// ------- bias precompute + weight fp16 conversion --------------------------
__global__ void k_bias(const float* __restrict__ rpb, const int* __restrict__ rpi,
                       float* __restrict__ bias_full,
                       const float* __restrict__ qkvw, const float* __restrict__ projw,
                       _Float16* __restrict__ wq, _Float16* __restrict__ wp) {
  int idx = blockIdx.x * 256 + threadIdx.x;
  int t = rpi[idx];
  float4 b4 = *reinterpret_cast<const float4*>(rpb + 4 * t);
  bias_full[0 * NTOT + idx] = b4.x;
  bias_full[1 * NTOT + idx] = b4.y;
  bias_full[2 * NTOT + idx] = b4.z;
  bias_full[3 * NTOT + idx] = b4.w;
  if (idx < 65536) {
    if (idx < 49152) wq[idx] = (_Float16)qkvw[idx];
    else             wp[idx - 49152] = (_Float16)projw[idx - 49152];
  }
}

// ------- fused roll + partition + QKV GEMM on fp16 MFMA --------------------
// grid 768 = 3 (q/k/v) x 256 (64 win x 4 row-tiles of 128 tokens); block 256.
// LDS: A,B fp16 [128][128], 16B slots XOR-swizzled by row&15. K=128 = one stage.
__global__ __launch_bounds__(256, 2) void k_qkv(
    const float* __restrict__ x, const _Float16* __restrict__ wq,
    const float* __restrict__ qkvb,
    __hip_bfloat16* __restrict__ qb, __hip_bfloat16* __restrict__ kb,
    __hip_bfloat16* __restrict__ vb) {
  __shared__ unsigned short As[128 * 128];
  __shared__ unsigned short Bs[128 * 128];
  const int tid = threadIdx.x;
  const int bm = blockIdx.x;
  const int nc = bm >> 8;              // 0=q 1=k 2=v
  const int mt = bm & 255;
  const int win = mt >> 2, t128 = mt & 3;
  const int wh = win >> 4, ww = (win >> 2) & 3, wd = win & 3;

  // stage A: 128 tokens x 128 ch, roll+partition gather, fp32 -> fp16
#pragma unroll
  for (int u = 0; u < 8; ++u) {
    int f = u * 256 + tid;             // 2048 units of 8 floats
    int row = f >> 4, seg = f & 15;
    int n = t128 * 128 + row;
    int lh = n >> 6, lw = (n >> 3) & 7, ld = n & 7;
    int sh = (wh * 8 + lh + 4) & 31;
    int sw = (ww * 8 + lw + 4) & 31;
    int sd = (wd * 8 + ld + 4) & 31;
    const float* src = x + ((sh * 32 + sw) * 32 + sd) * 128 + seg * 8;
    float4 a0 = *(const float4*)src;
    float4 a1 = *(const float4*)(src + 4);
    f16x8 hv;
    hv[0] = (_Float16)a0.x; hv[1] = (_Float16)a0.y;
    hv[2] = (_Float16)a0.z; hv[3] = (_Float16)a0.w;
    hv[4] = (_Float16)a1.x; hv[5] = (_Float16)a1.y;
    hv[6] = (_Float16)a1.z; hv[7] = (_Float16)a1.w;
    int slot = seg ^ (row & 15);
    *(u32x4*)(&As[row * 128 + slot * 8]) = __builtin_bit_cast(u32x4, hv);
  }
  // stage B: 128 weight rows (output cols nc*128..+128), already fp16
#pragma unroll
  for (int u = 0; u < 8; ++u) {
    int f = u * 256 + tid;
    int row = f >> 4, seg = f & 15;
    u32x4 wv = *(const u32x4*)(wq + (nc * 128 + row) * 128 + seg * 8);
    int slot = seg ^ (row & 15);
    *(u32x4*)(&Bs[row * 128 + slot * 8]) = wv;
  }
  __syncthreads();

  const int wave = tid >> 6, lane = tid & 63;
  const int lq = lane & 31, h = lane >> 5;
  const int wm = wave >> 1, wn = wave & 1;

  f32x16 a00, a01, a10, a11;
#pragma unroll
  for (int r = 0; r < 16; ++r) { a00[r] = 0.f; a01[r] = 0.f; a10[r] = 0.f; a11[r] = 0.f; }

#pragma unroll
  for (int ks = 0; ks < 8; ++ks) {
    int r0 = wm * 64 + lq, r1 = wm * 64 + 32 + lq;
    int c0 = wn * 64 + lq, c1 = wn * 64 + 32 + lq;
    int sl = ks * 2 + h;
    f16x8 af0 = __builtin_bit_cast(f16x8, *(const u32x4*)(&As[r0 * 128 + (sl ^ (r0 & 15)) * 8]));
    f16x8 af1 = __builtin_bit_cast(f16x8, *(const u32x4*)(&As[r1 * 128 + (sl ^ (r1 & 15)) * 8]));
    f16x8 bf0 = __builtin_bit_cast(f16x8, *(const u32x4*)(&Bs[c0 * 128 + (sl ^ (c0 & 15)) * 8]));
    f16x8 bf1 = __builtin_bit_cast(f16x8, *(const u32x4*)(&Bs[c1 * 128 + (sl ^ (c1 & 15)) * 8]));
    a00 = __builtin_amdgcn_mfma_f32_32x32x16_f16(af0, bf0, a00, 0, 0, 0);
    a01 = __builtin_amdgcn_mfma_f32_32x32x16_f16(af0, bf1, a01, 0, 0, 0);
    a10 = __builtin_amdgcn_mfma_f32_32x32x16_f16(af1, bf0, a10, 0, 0, 0);
    a11 = __builtin_amdgcn_mfma_f32_32x32x16_f16(af1, bf1, a11, 0, 0, 0);
  }

  // epilogue: +bias, q*scale, scatter bf16 to q/k ([whb][512][32]) or v^T
  const float scale = 0.17677669529663687f;
  float bias0 = qkvb[nc * 128 + wn * 64 + lq];
  float bias1 = qkvb[nc * 128 + wn * 64 + 32 + lq];

#define EPI_QK(ACC, MI, NI, DST, DO_SCALE)                                    \
  {                                                                           \
    int head = wn * 2 + (NI);                                                 \
    size_t whb = (size_t)(win * 4 + head);                                    \
    float bc = (NI) ? bias1 : bias0;                                          \
    _Pragma("unroll")                                                         \
    for (int r = 0; r < 16; ++r) {                                            \
      int row32 = (r & 3) + 8 * (r >> 2) + 4 * h;                             \
      int n = t128 * 128 + wm * 64 + (MI) * 32 + row32;                       \
      float val = ACC[r] + bc;                                                \
      if (DO_SCALE) val *= scale;                                             \
      DST[(whb * 512 + n) * 32 + lq] = __float2bfloat16(val);                 \
    }                                                                         \
  }
#define EPI_V(ACC, MI, NI)                                                    \
  {                                                                           \
    int head = wn * 2 + (NI);                                                 \
    size_t whb = (size_t)(win * 4 + head);                                    \
    float bc = (NI) ? bias1 : bias0;                                          \
    _Pragma("unroll")                                                         \
    for (int g = 0; g < 4; ++g) {                                             \
      int n0 = t128 * 128 + wm * 64 + (MI) * 32 + g * 8 + 4 * h;              \
      uint2 u = make_uint2(pkbf16(ACC[g * 4 + 0] + bc, ACC[g * 4 + 1] + bc),  \
                           pkbf16(ACC[g * 4 + 2] + bc, ACC[g * 4 + 3] + bc)); \
      *(uint2*)(vb + (whb * 32 + lq) * 512 + n0) = u;                         \
    }                                                                         \
  }

  if (nc == 0) {
    EPI_QK(a00, 0, 0, qb, 1); EPI_QK(a01, 0, 1, qb, 1);
    EPI_QK(a10, 1, 0, qb, 1); EPI_QK(a11, 1, 1, qb, 1);
  } else if (nc == 1) {
    EPI_QK(a00, 0, 0, kb, 0); EPI_QK(a01, 0, 1, kb, 0);
    EPI_QK(a10, 1, 0, kb, 0); EPI_QK(a11, 1, 1, kb, 0);
  } else {
    EPI_V(a00, 0, 0); EPI_V(a01, 0, 1);
    EPI_V(a10, 1, 0); EPI_V(a11, 1, 1);
  }
}

// ------- attention: bf16 MFMA, swapped-operand flash (ao now fp16) ---------
__global__ __launch_bounds__(256) void k_attn(
    const __hip_bfloat16* __restrict__ qb, const __hip_bfloat16* __restrict__ kb,
    const __hip_bfloat16* __restrict__ vb, const float* __restrict__ bias_full,
    _Float16* __restrict__ ao) {
  __shared__ unsigned short Ks[64 * 40];
  __shared__ unsigned short Vs[32 * 72];
  __shared__ unsigned char regid[512];

  const int tid = threadIdx.x;
  const int b = blockIdx.x;
  const int win = b >> 4, head = (b >> 2) & 3, qblk = b & 3;
  const int wh = win >> 4, ww = (win >> 2) & 3, wd = win & 3;
  const int wave = tid >> 6, lane = tid & 63;
  const int lq = lane & 31, h = lane >> 5;
  const int q = qblk * 128 + wave * 32 + lq;

#pragma unroll
  for (int i = 0; i < 2; ++i) {
    int n = tid + i * 256;
    int lh = n >> 6, lw = (n >> 3) & 7, ld = n & 7;
    regid[n] = (unsigned char)(((wh == 3) ? (lh < 4 ? 1 : 2) : 0) * 9 +
                               ((ww == 3) ? (lw < 4 ? 1 : 2) : 0) * 3 +
                               ((wd == 3) ? (ld < 4 ? 1 : 2) : 0));
  }
  const int qlh = q >> 6, qlw = (q >> 3) & 7, qld = q & 7;
  const unsigned int rn =
      (unsigned)(((wh == 3) ? (qlh < 4 ? 1 : 2) : 0) * 9 +
                 ((ww == 3) ? (qlw < 4 ? 1 : 2) : 0) * 3 +
                 ((wd == 3) ? (qld < 4 ? 1 : 2) : 0));

  const size_t whb = (size_t)(win * 4 + head);
  const __hip_bfloat16* qrow = qb + (whb * 512 + q) * 32;
  bf16x8 qf0 = __builtin_bit_cast(bf16x8, *(const u32x4*)(qrow + h * 8));
  bf16x8 qf1 = __builtin_bit_cast(bf16x8, *(const u32x4*)(qrow + 16 + h * 8));

  const __hip_bfloat16* kg = kb + whb * 512 * 32;
  const __hip_bfloat16* vg = vb + whb * 32 * 512;
  const float* brow = bias_full + ((size_t)head * 512 + q) * 512;

  float m_run = -3.0e38f, l_run = 0.f;
  f32x16 o;
#pragma unroll
  for (int r = 0; r < 16; ++r) o[r] = 0.f;

  for (int chk = 0; chk < 8; ++chk) {
    __syncthreads();
    {
      int row = tid >> 2, seg = tid & 3;
      *(u32x4*)(&Ks[row * 40 + seg * 8]) =
          *(const u32x4*)(kg + (chk * 64 + row) * 32 + seg * 8);
      int d = tid >> 3, seg2 = tid & 7;
      *(u32x4*)(&Vs[d * 72 + seg2 * 8]) =
          *(const u32x4*)(vg + d * 512 + chk * 64 + seg2 * 8);
    }
    __syncthreads();

#pragma unroll
    for (int sub = 0; sub < 2; ++sub) {
      const int kbase = chk * 64 + sub * 32;

      bf16x8 kf0 = __builtin_bit_cast(bf16x8,
          *(const u32x4*)(&Ks[(sub * 32 + lq) * 40 + h * 8]));
      bf16x8 kf1 = __builtin_bit_cast(bf16x8,
          *(const u32x4*)(&Ks[(sub * 32 + lq) * 40 + 16 + h * 8]));
      f32x16 c;
#pragma unroll
      for (int r = 0; r < 16; ++r) c[r] = 0.f;
      c = __builtin_amdgcn_mfma_f32_32x32x16_bf16(kf0, qf0, c, 0, 0, 0);
      c = __builtin_amdgcn_mfma_f32_32x32x16_bf16(kf1, qf1, c, 0, 0, 0);

      float bias_s[16];
      unsigned int rm4[4];
#pragma unroll
      for (int j = 0; j < 4; ++j) {
        float4 b4 = *(const float4*)(brow + kbase + h * 4 + j * 8);
        bias_s[j * 4 + 0] = b4.x; bias_s[j * 4 + 1] = b4.y;
        bias_s[j * 4 + 2] = b4.z; bias_s[j * 4 + 3] = b4.w;
        rm4[j] = *(const unsigned int*)(&regid[kbase + h * 4 + j * 8]);
      }

      float s[16];
#pragma unroll
      for (int r = 0; r < 16; ++r) {
        int j = r >> 2, i = r & 3;
        float mval = (((rm4[j] >> (8 * i)) & 255u) == rn) ? 0.f : -100.f;
        s[r] = c[r] + bias_s[r] + mval;
      }

      float tmax = s[0];
#pragma unroll
      for (int r = 1; r < 16; ++r) tmax = fmaxf(tmax, s[r]);
      tmax = fmaxf(tmax, __shfl_xor(tmax, 32, 64));
      float m_new = fmaxf(m_run, tmax);
      float alpha = __expf(m_run - m_new);
      float p[16], lsum = 0.f;
#pragma unroll
      for (int r = 0; r < 16; ++r) { p[r] = __expf(s[r] - m_new); lsum += p[r]; }
      lsum += __shfl_xor(lsum, 32, 64);
      l_run = l_run * alpha + lsum;
      m_run = m_new;
#pragma unroll
      for (int r = 0; r < 16; ++r) o[r] *= alpha;

      unsigned int bw[8];
#pragma unroll
      for (int g = 0; g < 8; ++g) bw[g] = pkbf16(p[2 * g], p[2 * g + 1]);

#pragma unroll
      for (int kc = 0; kc < 2; ++kc) {
        unsigned int b0 = bw[kc * 4 + 0], b1 = bw[kc * 4 + 1];
        unsigned int b2 = bw[kc * 4 + 2], b3 = bw[kc * 4 + 3];
        unsigned int sb0 = __shfl_xor(b0, 32, 64), sb1 = __shfl_xor(b1, 32, 64);
        unsigned int sb2 = __shfl_xor(b2, 32, 64), sb3 = __shfl_xor(b3, 32, 64);
        u32x4 pw;
        pw.x = h ? sb2 : b0;
        pw.y = h ? sb3 : b1;
        pw.z = h ? b2 : sb0;
        pw.w = h ? b3 : sb1;
        bf16x8 pf = __builtin_bit_cast(bf16x8, pw);
        bf16x8 vf = __builtin_bit_cast(bf16x8,
            *(const u32x4*)(&Vs[lq * 72 + sub * 32 + kc * 16 + h * 8]));
        o = __builtin_amdgcn_mfma_f32_32x32x16_bf16(vf, pf, o, 0, 0, 0);
      }
    }
  }

  const float inv = 1.f / l_run;
  _Float16* orow = ao + ((size_t)(win * 512 + q)) * 128 + head * 32;
#pragma unroll
  for (int j = 0; j < 4; ++j) {
    int d0 = j * 8 + h * 4;
    f16x4 t;
    t[0] = (_Float16)(o[j * 4 + 0] * inv);
    t[1] = (_Float16)(o[j * 4 + 1] * inv);
    t[2] = (_Float16)(o[j * 4 + 2] * inv);
    t[3] = (_Float16)(o[j * 4 + 3] * inv);
    *(f16x4*)(orow + d0) = t;
  }
}

// ------- proj GEMM (fp16 MFMA) + reverse partition + reverse roll ----------
// grid 256 = 64 win x 4 row-tiles; block 256. N=128 single tile.
__global__ __launch_bounds__(256, 2) void k_proj(
    const _Float16* __restrict__ ao, const _Float16* __restrict__ wp,
    const float* __restrict__ pb, float* __restrict__ out) {
  __shared__ unsigned short As[128 * 128];
  __shared__ unsigned short Bs[128 * 128];
  const int tid = threadIdx.x;
  const int mt = blockIdx.x;
  const int win = mt >> 2, t128 = mt & 3;
  const int wh = win >> 4, ww = (win >> 2) & 3, wd = win & 3;

#pragma unroll
  for (int u = 0; u < 8; ++u) {
    int f = u * 256 + tid;
    int row = f >> 4, seg = f & 15;
    u32x4 av = *(const u32x4*)(ao + ((size_t)(win * 512 + t128 * 128 + row)) * 128 + seg * 8);
    int slot = seg ^ (row & 15);
    *(u32x4*)(&As[row * 128 + slot * 8]) = av;
  }
#pragma unroll
  for (int u = 0; u < 8; ++u) {
    int f = u * 256 + tid;
    int row = f >> 4, seg = f & 15;
    u32x4 wv = *(const u32x4*)(wp + row * 128 + seg * 8);
    int slot = seg ^ (row & 15);
    *(u32x4*)(&Bs[row * 128 + slot * 8]) = wv;
  }
  __syncthreads();

  const int wave = tid >> 6, lane = tid & 63;
  const int lq = lane & 31, h = lane >> 5;
  const int wm = wave >> 1, wn = wave & 1;

  f32x16 a00, a01, a10, a11;
#pragma unroll
  for (int r = 0; r < 16; ++r) { a00[r] = 0.f; a01[r] = 0.f; a10[r] = 0.f; a11[r] = 0.f; }

#pragma unroll
  for (int ks = 0; ks < 8; ++ks) {
    int r0 = wm * 64 + lq, r1 = wm * 64 + 32 + lq;
    int c0 = wn * 64 + lq, c1 = wn * 64 + 32 + lq;
    int sl = ks * 2 + h;
    f16x8 af0 = __builtin_bit_cast(f16x8, *(const u32x4*)(&As[r0 * 128 + (sl ^ (r0 & 15)) * 8]));
    f16x8 af1 = __builtin_bit_cast(f16x8, *(const u32x4*)(&As[r1 * 128 + (sl ^ (r1 & 15)) * 8]));
    f16x8 bf0 = __builtin_bit_cast(f16x8, *(const u32x4*)(&Bs[c0 * 128 + (sl ^ (c0 & 15)) * 8]));
    f16x8 bf1 = __builtin_bit_cast(f16x8, *(const u32x4*)(&Bs[c1 * 128 + (sl ^ (c1 & 15)) * 8]));
    a00 = __builtin_amdgcn_mfma_f32_32x32x16_f16(af0, bf0, a00, 0, 0, 0);
    a01 = __builtin_amdgcn_mfma_f32_32x32x16_f16(af0, bf1, a01, 0, 0, 0);
    a10 = __builtin_amdgcn_mfma_f32_32x32x16_f16(af1, bf0, a10, 0, 0, 0);
    a11 = __builtin_amdgcn_mfma_f32_32x32x16_f16(af1, bf1, a11, 0, 0, 0);
  }

  float bias0 = pb[wn * 64 + lq];
  float bias1 = pb[wn * 64 + 32 + lq];

#define EPI_P(ACC, MI, NI)                                                    \
  {                                                                           \
    int col = wn * 64 + (NI) * 32 + lq;                                       \
    float bc = (NI) ? bias1 : bias0;                                          \
    _Pragma("unroll")                                                         \
    for (int r = 0; r < 16; ++r) {                                            \
      int row32 = (r & 3) + 8 * (r >> 2) + 4 * h;                             \
      int n = t128 * 128 + wm * 64 + (MI) * 32 + row32;                       \
      int lh = n >> 6, lw = (n >> 3) & 7, ld = n & 7;                         \
      int dh = (wh * 8 + lh + 4) & 31;                                        \
      int dw = (ww * 8 + lw + 4) & 31;                                        \
      int dd = (wd * 8 + ld + 4) & 31;                                        \
      out[(size_t)((dh * 32 + dw) * 32 + dd) * 128 + col] = ACC[r] + bc;      \
    }                                                                         \
  }
  EPI_P(a00, 0, 0); EPI_P(a01, 0, 1); EPI_P(a10, 1, 0); EPI_P(a11, 1, 1);
}

extern "C" void kernel_launch(void* const* d_in, const int* in_sizes, int n_in,
                              void* d_out, int out_size, void* d_ws, size_t ws_size,
                              hipStream_t stream) {
  const float* x    = (const float*)d_in[0];
  const float* qkvw = (const float*)d_in[1];
  const float* qkvb = (const float*)d_in[2];
  const float* pw   = (const float*)d_in[3];
  const float* pb   = (const float*)d_in[4];
  const float* rpb  = (const float*)d_in[5];
  const int*   rpi  = (const int*)d_in[6];
  float* out = (float*)d_out;

  char* base = (char*)d_ws;
  __hip_bfloat16* qbuf = (__hip_bfloat16*)(base);
  __hip_bfloat16* kbuf = (__hip_bfloat16*)(base + 8388608);
  __hip_bfloat16* vbuf = (__hip_bfloat16*)(base + 16777216);
  _Float16* ao = (_Float16*)(base + 25165824);
  float* bf = (float*)(base + 33554432);
  _Float16* wq = (_Float16*)(base + 37748736);
  _Float16* wp = (_Float16*)(base + 37847040);

  hipLaunchKernelGGL(k_bias, dim3(1024), dim3(256), 0, stream, rpb, rpi, bf, qkvw, pw, wq, wp);
  hipLaunchKernelGGL(k_qkv,  dim3(768),  dim3(256), 0, stream, x, wq, qkvb, qbuf, kbuf, vbuf);
  hipLaunchKernelGGL(k_attn, dim3(1024), dim3(256), 0, stream, qbuf, kbuf, vbuf, bf, ao);
  hipLaunchKernelGGL(k_proj, dim3(256),  dim3(256), 0, stream, ao, wp, pb, out);
}